// Round 1
// baseline (483.235 us; speedup 1.0000x reference)
//
#include <hip/hip_runtime.h>
#include <hip/hip_bf16.h>

typedef short s8v __attribute__((ext_vector_type(8)));   // 8 bf16 = 16B (4 VGPR)
typedef float f4v __attribute__((ext_vector_type(4)));   // MFMA accum

#define MFMA_BF16(a, b, c) __builtin_amdgcn_mfma_f32_16x16x32_bf16((a), (b), (c), 0, 0, 0)

__device__ __forceinline__ short f2bf(float f) {
  __hip_bfloat16 h = __float2bfloat16(f);
  return *reinterpret_cast<short*>(&h);
}
__device__ __forceinline__ float bf2f(short s) {
  __hip_bfloat16 h;
  *reinterpret_cast<short*>(&h) = s;
  return __bfloat162float(h);
}

// ---------------- fp32 -> bf16 conversion (x and the three W) ----------------
__global__ __launch_bounds__(256) void cvt_kernel(const float* __restrict__ in,
                                                  short* __restrict__ out, int n8) {
  int i = blockIdx.x * 256 + threadIdx.x;
  if (i >= n8) return;
  const float* p = in + (size_t)i * 8;
  float4 a = *(const float4*)p;
  float4 b = *(const float4*)(p + 4);
  s8v o;
  o[0] = f2bf(a.x); o[1] = f2bf(a.y); o[2] = f2bf(a.z); o[3] = f2bf(a.w);
  o[4] = f2bf(b.x); o[5] = f2bf(b.y); o[6] = f2bf(b.z); o[7] = f2bf(b.w);
  *(s8v*)(out + (size_t)i * 8) = o;
}

// ---------------- projections: y = x @ W^T + b, bf16 MFMA ----------------
// x_bf: (32768, 512), W_bf: (3, 512, 512) row-major (row m = output col), out bf16.
__global__ __launch_bounds__(256) void proj_kernel(
    const short* __restrict__ xb, const short* __restrict__ wb,
    const float* __restrict__ bq, const float* __restrict__ bk, const float* __restrict__ bv,
    short* __restrict__ qo, short* __restrict__ ko, short* __restrict__ vo) {
  const int rb = blockIdx.x;   // 0..255  (rows of 128)
  const int cb = blockIdx.y;   // 0..3    (cols of 128)
  const int mat = blockIdx.z;  // 0..2
  const int R0 = rb * 128, C0 = cb * 128;
  const short* w = wb + (size_t)mat * 512 * 512;
  const float* bias = (mat == 0) ? bq : (mat == 1) ? bk : bv;
  short* out = (mat == 0) ? qo : (mat == 1) ? ko : vo;

  // padded rows (40 shorts = 80B): even bank spread for b128 reads, 16B aligned
  __shared__ short xs[128 * 40];
  __shared__ short wsh[128 * 40];

  const int t = threadIdx.x;
  const int lane = t & 63, wv = t >> 6;
  const int wr = (wv >> 1) * 64, wc = (wv & 1) * 64;
  const int lr = lane & 15, lk = (lane >> 4) * 8;

  f4v acc[4][4];
  #pragma unroll
  for (int i = 0; i < 4; i++)
    #pragma unroll
    for (int j = 0; j < 4; j++) acc[i][j] = (f4v){0.f, 0.f, 0.f, 0.f};

  const int sr = t >> 1, sh = (t & 1) * 16;  // staging row / half (16 shorts)
  const short* xsrc = xb + (size_t)(R0 + sr) * 512 + sh;
  const short* wsrc = w + (size_t)(C0 + sr) * 512 + sh;

  for (int kk = 0; kk < 16; ++kk) {
    s8v a0 = *(const s8v*)(xsrc + kk * 32);
    s8v a1 = *(const s8v*)(xsrc + kk * 32 + 8);
    s8v b0 = *(const s8v*)(wsrc + kk * 32);
    s8v b1 = *(const s8v*)(wsrc + kk * 32 + 8);
    *(s8v*)&xs[sr * 40 + sh] = a0;
    *(s8v*)&xs[sr * 40 + sh + 8] = a1;
    *(s8v*)&wsh[sr * 40 + sh] = b0;
    *(s8v*)&wsh[sr * 40 + sh + 8] = b1;
    __syncthreads();
    s8v af[4], bf[4];
    #pragma unroll
    for (int mf = 0; mf < 4; ++mf) af[mf] = *(const s8v*)&xs[(wr + mf * 16 + lr) * 40 + lk];
    #pragma unroll
    for (int nf = 0; nf < 4; ++nf) bf[nf] = *(const s8v*)&wsh[(wc + nf * 16 + lr) * 40 + lk];
    #pragma unroll
    for (int mf = 0; mf < 4; ++mf)
      #pragma unroll
      for (int nf = 0; nf < 4; ++nf)
        acc[mf][nf] = MFMA_BF16(af[mf], bf[nf], acc[mf][nf]);
    __syncthreads();
  }
  // epilogue: + bias, cast bf16, store
  #pragma unroll
  for (int nf = 0; nf < 4; ++nf) {
    int col = C0 + wc + nf * 16 + lr;
    float bb = bias[col];
    #pragma unroll
    for (int mf = 0; mf < 4; ++mf)
      #pragma unroll
      for (int i = 0; i < 4; i++) {
        int row = R0 + wr + mf * 16 + (lane >> 4) * 4 + i;
        out[(size_t)row * 512 + col] = f2bf(acc[mf][nf][i] + bb);
      }
  }
}

// ---------------- v (B,C,N) -> v_t (B,N,C), bf16 ----------------
__global__ __launch_bounds__(256) void transpose_kernel(const short* __restrict__ v,
                                                        short* __restrict__ vt) {
  const int nb = blockIdx.x;   // 0..7   (N/64)
  const int cbk = blockIdx.y;  // 0..15  (C/64)
  const int b = blockIdx.z;    // 0..31
  __shared__ short tile[64 * 72];
  const int t = threadIdx.x;
  const int r = t >> 2, qd = t & 3;
  const short* src = v + (size_t)(b * 1024 + cbk * 64 + r) * 512 + nb * 64 + qd * 16;
  s8v v0 = *(const s8v*)src;
  s8v v1 = *(const s8v*)(src + 8);
  *(s8v*)&tile[r * 72 + qd * 16] = v0;
  *(s8v*)&tile[r * 72 + qd * 16 + 8] = v1;
  __syncthreads();
  s8v o0, o1;
  #pragma unroll
  for (int j = 0; j < 8; j++) o0[j] = tile[(qd * 16 + j) * 72 + r];
  #pragma unroll
  for (int j = 0; j < 8; j++) o1[j] = tile[(qd * 16 + 8 + j) * 72 + r];
  short* dst = vt + (size_t)(b * 512 + nb * 64 + r) * 1024 + cbk * 64 + qd * 16;
  *(s8v*)dst = o0;
  *(s8v*)(dst + 8) = o1;
}

// ---------------- flash attention + beta residual ----------------
// block = (batch b, 32 q-rows); 4 waves, wave owns out cols [128w,128w+128)
__global__ __launch_bounds__(256) void attn_kernel(
    const short* __restrict__ qb, const short* __restrict__ kb,
    const short* __restrict__ vb, const short* __restrict__ vt,
    const float* __restrict__ beta_p, float* __restrict__ outp) {
  const int bx = blockIdx.x;
  const int b = bx >> 5;
  const int q0 = (bx & 31) * 32;
  const int t = threadIdx.x, lane = t & 63, wv = t >> 6;
  const int lr = lane & 15, lk = (lane >> 4) * 8;

  __shared__ float Es[32 * 68];   // energy tile, padded rows (272B)
  __shared__ short Ps[32 * 72];   // P bf16, padded rows (144B)
  __shared__ float m_s[32], l_s[32], sc_s[32];

  if (t < 32) { m_s[t] = -3.0e38f; l_s[t] = 0.0f; }

  // Q fragments in registers: rows q0..q0+32, full K=512
  const short* qq = qb + (size_t)(b * 1024 + q0) * 512;
  s8v Qf[2][16];
  #pragma unroll
  for (int mi = 0; mi < 2; ++mi)
    #pragma unroll
    for (int ks = 0; ks < 16; ++ks)
      Qf[mi][ks] = *(const s8v*)(qq + (size_t)(mi * 16 + lr) * 512 + ks * 32 + lk);

  f4v acc[2][8];
  #pragma unroll
  for (int mi = 0; mi < 2; ++mi)
    #pragma unroll
    for (int nf = 0; nf < 8; ++nf) acc[mi][nf] = (f4v){0.f, 0.f, 0.f, 0.f};

  __syncthreads();

  const short* kk_ = kb + (size_t)b * 1024 * 512;
  const short* vt_ = vt + (size_t)b * 512 * 1024;

  for (int dt = 0; dt < 16; ++dt) {
    const int d0 = dt * 64;
    // ---- QK^T : wave w computes energy[0:32][16w:16w+16]
    f4v e0 = (f4v){0.f, 0.f, 0.f, 0.f};
    f4v e1 = (f4v){0.f, 0.f, 0.f, 0.f};
    const short* krow = kk_ + (size_t)(d0 + wv * 16 + lr) * 512 + lk;
    #pragma unroll
    for (int ks = 0; ks < 16; ++ks) {
      s8v bfk = *(const s8v*)(krow + ks * 32);
      e0 = MFMA_BF16(Qf[0][ks], bfk, e0);
      e1 = MFMA_BF16(Qf[1][ks], bfk, e1);
    }
    #pragma unroll
    for (int i = 0; i < 4; i++) {
      Es[((lane >> 4) * 4 + i) * 68 + wv * 16 + lr] = e0[i];
      Es[(16 + (lane >> 4) * 4 + i) * 68 + wv * 16 + lr] = e1[i];
    }
    __syncthreads();
    // ---- online softmax: row r handled by 8 lanes (8 cols each)
    {
      const int r = wv * 8 + (lane >> 3);
      const int cg = lane & 7;
      float ev[8];
      *(float4*)&ev[0] = *(const float4*)&Es[r * 68 + cg * 8];
      *(float4*)&ev[4] = *(const float4*)&Es[r * 68 + cg * 8 + 4];
      float tm = ev[0];
      #pragma unroll
      for (int j = 1; j < 8; j++) tm = fmaxf(tm, ev[j]);
      tm = fmaxf(tm, __shfl_xor(tm, 1));
      tm = fmaxf(tm, __shfl_xor(tm, 2));
      tm = fmaxf(tm, __shfl_xor(tm, 4));
      float m_old = m_s[r];
      float mn = fmaxf(m_old, tm);
      float p[8];
      float ts = 0.f;
      #pragma unroll
      for (int j = 0; j < 8; j++) { p[j] = __expf(ev[j] - mn); ts += p[j]; }
      ts += __shfl_xor(ts, 1);
      ts += __shfl_xor(ts, 2);
      ts += __shfl_xor(ts, 4);
      float sc = __expf(m_old - mn);
      if (cg == 0) {
        l_s[r] = l_s[r] * sc + ts;
        m_s[r] = mn;
        sc_s[r] = sc;
      }
      s8v pvv;
      #pragma unroll
      for (int j = 0; j < 8; j++) pvv[j] = f2bf(p[j]);
      *(s8v*)&Ps[r * 72 + cg * 8] = pvv;
    }
    __syncthreads();
    // ---- rescale accumulators by exp(m_old - m_new)
    float srow[2][4];
    #pragma unroll
    for (int mi = 0; mi < 2; ++mi)
      #pragma unroll
      for (int i = 0; i < 4; ++i) srow[mi][i] = sc_s[mi * 16 + (lane >> 4) * 4 + i];
    #pragma unroll
    for (int mi = 0; mi < 2; ++mi)
      #pragma unroll
      for (int nf = 0; nf < 8; ++nf)
        #pragma unroll
        for (int i = 0; i < 4; ++i) acc[mi][nf][i] *= srow[mi][i];
    // ---- PV: acc += P[32x64] * V[64x128w-slice]
    s8v pa[2][2];
    #pragma unroll
    for (int mi = 0; mi < 2; ++mi)
      #pragma unroll
      for (int k2 = 0; k2 < 2; ++k2)
        pa[mi][k2] = *(const s8v*)&Ps[(mi * 16 + lr) * 72 + k2 * 32 + lk];
    #pragma unroll
    for (int nf = 0; nf < 8; ++nf) {
      const short* vrow = vt_ + (size_t)(wv * 128 + nf * 16 + lr) * 1024 + d0 + lk;
      #pragma unroll
      for (int k2 = 0; k2 < 2; ++k2) {
        s8v bvv = *(const s8v*)(vrow + k2 * 32);
        acc[0][nf] = MFMA_BF16(pa[0][k2], bvv, acc[0][nf]);
        acc[1][nf] = MFMA_BF16(pa[1][k2], bvv, acc[1][nf]);
      }
    }
    __syncthreads();
  }
  // ---- epilogue: out = beta * (acc / l) + v
  const float beta = beta_p[0];
  const short* vres = vb + (size_t)(b * 1024 + q0) * 512;
  float invl[2][4];
  #pragma unroll
  for (int mi = 0; mi < 2; ++mi)
    #pragma unroll
    for (int i = 0; i < 4; ++i)
      invl[mi][i] = 1.0f / l_s[mi * 16 + (lane >> 4) * 4 + i];
  #pragma unroll
  for (int mi = 0; mi < 2; ++mi)
    #pragma unroll
    for (int nf = 0; nf < 8; ++nf)
      #pragma unroll
      for (int i = 0; i < 4; ++i) {
        int row = mi * 16 + (lane >> 4) * 4 + i;
        int col = wv * 128 + nf * 16 + lr;
        float val = beta * acc[mi][nf][i] * invl[mi][i] + bf2f(vres[(size_t)row * 512 + col]);
        outp[(size_t)(b * 1024 + q0 + row) * 512 + col] = val;
      }
}

extern "C" void kernel_launch(void* const* d_in, const int* in_sizes, int n_in,
                              void* d_out, int out_size, void* d_ws, size_t ws_size,
                              hipStream_t stream) {
  (void)in_sizes; (void)n_in; (void)out_size; (void)ws_size;
  const float* x = (const float*)d_in[0];
  const float* Wq = (const float*)d_in[1];
  const float* bq = (const float*)d_in[2];
  const float* Wk = (const float*)d_in[3];
  const float* bk = (const float*)d_in[4];
  const float* Wv = (const float*)d_in[5];
  const float* bv = (const float*)d_in[6];
  const float* beta = (const float*)d_in[7];
  float* out = (float*)d_out;

  char* ws = (char*)d_ws;
  short* xb = (short*)(ws);                  // 33,554,432 B (reused as v_t later)
  short* wb = (short*)(ws + 33554432);       //  1,572,864 B
  short* qb = (short*)(ws + 35127296);       // 33,554,432 B
  short* kb = (short*)(ws + 68681728);       // 33,554,432 B
  short* vb = (short*)(ws + 102236160);      // 33,554,432 B  (total ~136 MB)
  short* vt = xb;                            // alias: x_bf dead after proj

  cvt_kernel<<<8192, 256, 0, stream>>>(x, xb, 2097152);
  cvt_kernel<<<128, 256, 0, stream>>>(Wq, wb, 32768);
  cvt_kernel<<<128, 256, 0, stream>>>(Wk, wb + 262144, 32768);
  cvt_kernel<<<128, 256, 0, stream>>>(Wv, wb + 524288, 32768);
  proj_kernel<<<dim3(256, 4, 3), 256, 0, stream>>>(xb, wb, bq, bk, bv, qb, kb, vb);
  transpose_kernel<<<dim3(8, 16, 32), 256, 0, stream>>>(vb, vt);
  attn_kernel<<<1024, 256, 0, stream>>>(qb, kb, vb, vt, beta, out);
}

// Round 2
// 480.818 us; speedup vs baseline: 1.0050x; 1.0050x over previous
//
#include <hip/hip_runtime.h>
#include <hip/hip_bf16.h>

typedef short s8v __attribute__((ext_vector_type(8)));   // 8 bf16 = 16B (4 VGPR)
typedef float f4v __attribute__((ext_vector_type(4)));   // MFMA accum

#define MFMA_BF16(a, b, c) __builtin_amdgcn_mfma_f32_16x16x32_bf16((a), (b), (c), 0, 0, 0)

__device__ __forceinline__ short f2bf(float f) {
  __hip_bfloat16 h = __float2bfloat16(f);
  return *reinterpret_cast<short*>(&h);
}
__device__ __forceinline__ float bf2f(short s) {
  __hip_bfloat16 h;
  *reinterpret_cast<short*>(&h) = s;
  return __bfloat162float(h);
}

// ---------------- fp32 -> bf16 conversion (x and the three W) ----------------
__global__ __launch_bounds__(256) void cvt_kernel(const float* __restrict__ in,
                                                  short* __restrict__ out, int n8) {
  int i = blockIdx.x * 256 + threadIdx.x;
  if (i >= n8) return;
  const float* p = in + (size_t)i * 8;
  float4 a = *(const float4*)p;
  float4 b = *(const float4*)(p + 4);
  s8v o;
  o[0] = f2bf(a.x); o[1] = f2bf(a.y); o[2] = f2bf(a.z); o[3] = f2bf(a.w);
  o[4] = f2bf(b.x); o[5] = f2bf(b.y); o[6] = f2bf(b.z); o[7] = f2bf(b.w);
  *(s8v*)(out + (size_t)i * 8) = o;
}

// ---------------- projections: y = x @ W^T + b, bf16 MFMA ----------------
__global__ __launch_bounds__(256) void proj_kernel(
    const short* __restrict__ xb, const short* __restrict__ wb,
    const float* __restrict__ bq, const float* __restrict__ bk, const float* __restrict__ bv,
    short* __restrict__ qo, short* __restrict__ ko, short* __restrict__ vo) {
  const int rb = blockIdx.x;   // 0..255  (rows of 128)
  const int cb = blockIdx.y;   // 0..3    (cols of 128)
  const int mat = blockIdx.z;  // 0..2
  const int R0 = rb * 128, C0 = cb * 128;
  const short* w = wb + (size_t)mat * 512 * 512;
  const float* bias = (mat == 0) ? bq : (mat == 1) ? bk : bv;
  short* out = (mat == 0) ? qo : (mat == 1) ? ko : vo;

  __shared__ short xs[128 * 40];
  __shared__ short wsh[128 * 40];

  const int t = threadIdx.x;
  const int lane = t & 63, wv = t >> 6;
  const int wr = (wv >> 1) * 64, wc = (wv & 1) * 64;
  const int lr = lane & 15, lk = (lane >> 4) * 8;

  f4v acc[4][4];
  #pragma unroll
  for (int i = 0; i < 4; i++)
    #pragma unroll
    for (int j = 0; j < 4; j++) acc[i][j] = (f4v){0.f, 0.f, 0.f, 0.f};

  const int sr = t >> 1, sh = (t & 1) * 16;
  const short* xsrc = xb + (size_t)(R0 + sr) * 512 + sh;
  const short* wsrc = w + (size_t)(C0 + sr) * 512 + sh;

  for (int kk = 0; kk < 16; ++kk) {
    s8v a0 = *(const s8v*)(xsrc + kk * 32);
    s8v a1 = *(const s8v*)(xsrc + kk * 32 + 8);
    s8v b0 = *(const s8v*)(wsrc + kk * 32);
    s8v b1 = *(const s8v*)(wsrc + kk * 32 + 8);
    *(s8v*)&xs[sr * 40 + sh] = a0;
    *(s8v*)&xs[sr * 40 + sh + 8] = a1;
    *(s8v*)&wsh[sr * 40 + sh] = b0;
    *(s8v*)&wsh[sr * 40 + sh + 8] = b1;
    __syncthreads();
    s8v af[4], bf[4];
    #pragma unroll
    for (int mf = 0; mf < 4; ++mf) af[mf] = *(const s8v*)&xs[(wr + mf * 16 + lr) * 40 + lk];
    #pragma unroll
    for (int nf = 0; nf < 4; ++nf) bf[nf] = *(const s8v*)&wsh[(wc + nf * 16 + lr) * 40 + lk];
    #pragma unroll
    for (int mf = 0; mf < 4; ++mf)
      #pragma unroll
      for (int nf = 0; nf < 4; ++nf)
        acc[mf][nf] = MFMA_BF16(af[mf], bf[nf], acc[mf][nf]);
    __syncthreads();
  }
  #pragma unroll
  for (int nf = 0; nf < 4; ++nf) {
    int col = C0 + wc + nf * 16 + lr;
    float bb = bias[col];
    #pragma unroll
    for (int mf = 0; mf < 4; ++mf)
      #pragma unroll
      for (int i = 0; i < 4; i++) {
        int row = R0 + wr + mf * 16 + (lane >> 4) * 4 + i;
        out[(size_t)row * 512 + col] = f2bf(acc[mf][nf][i] + bb);
      }
  }
}

// ---------------- v (B,C,N) -> v_t (B,N,C), bf16 ----------------
__global__ __launch_bounds__(256) void transpose_kernel(const short* __restrict__ v,
                                                        short* __restrict__ vt) {
  const int nb = blockIdx.x;   // 0..7   (N/64)
  const int cbk = blockIdx.y;  // 0..15  (C/64)
  const int b = blockIdx.z;    // 0..31
  __shared__ short tile[64 * 72];
  const int t = threadIdx.x;
  const int r = t >> 2, qd = t & 3;
  const short* src = v + (size_t)(b * 1024 + cbk * 64 + r) * 512 + nb * 64 + qd * 16;
  s8v v0 = *(const s8v*)src;
  s8v v1 = *(const s8v*)(src + 8);
  *(s8v*)&tile[r * 72 + qd * 16] = v0;
  *(s8v*)&tile[r * 72 + qd * 16 + 8] = v1;
  __syncthreads();
  s8v o0, o1;
  #pragma unroll
  for (int j = 0; j < 8; j++) o0[j] = tile[(qd * 16 + j) * 72 + r];
  #pragma unroll
  for (int j = 0; j < 8; j++) o1[j] = tile[(qd * 16 + 8 + j) * 72 + r];
  short* dst = vt + (size_t)(b * 512 + nb * 64 + r) * 1024 + cbk * 64 + qd * 16;
  *(s8v*)dst = o0;
  *(s8v*)(dst + 8) = o1;
}

// ---------------- flash attention + beta residual (v2) ----------------
// block = 32 q-rows; 4 waves; KVBLK=64; E/P double-buffered; raw barriers
// (lgkmcnt-only) keep V-prefetch loads in flight; XCD-swizzled block ids.
__global__ __launch_bounds__(256, 2) void attn_kernel(
    const short* __restrict__ qb, const short* __restrict__ kb,
    const short* __restrict__ vb, const short* __restrict__ vt,
    const float* __restrict__ beta_p, float* __restrict__ outp) {
  const int bx = blockIdx.x;
  const int wg = (bx & 7) * 128 + (bx >> 3);   // bijective XCD swizzle (1024 % 8 == 0)
  const int b = wg >> 5;
  const int q0 = (wg & 31) * 32;
  const int t = threadIdx.x, lane = t & 63, wv = t >> 6;
  const int lr = lane & 15, lg = lane >> 4, lk = lg * 8;
  const int qh = wv & 1, kw = wv >> 1;   // QK^T: q-half, 32-key-quarter

  __shared__ float Es[2][32 * 68];
  __shared__ short Ps[2][32 * 72];
  __shared__ float sc_s[2][32];
  __shared__ float l_s[32];

  // Q fragments: wave's 16 rows [q0+16*qh, +16), full K=512 -> 64 VGPRs
  const short* qq = qb + (size_t)(b * 1024 + q0 + 16 * qh) * 512;
  s8v Qf[16];
  #pragma unroll
  for (int ks = 0; ks < 16; ++ks)
    Qf[ks] = *(const s8v*)(qq + (size_t)lr * 512 + ks * 32 + lk);

  f4v acc[2][8];
  #pragma unroll
  for (int mi = 0; mi < 2; ++mi)
    #pragma unroll
    for (int nf = 0; nf < 8; ++nf) acc[mi][nf] = (f4v){0.f, 0.f, 0.f, 0.f};

  float m_run = -3.0e38f, l_run = 0.0f;
  const int r = wv * 8 + (lane >> 3);   // softmax row owned by this lane
  const int cg = lane & 7;              // 8 lanes per row, 8 cols each

  const short* kk_ = kb + (size_t)b * 1024 * 512;
  const short* vt_ = vt + (size_t)b * 512 * 1024;

  for (int dt = 0; dt < 16; ++dt) {
    const int d0 = dt * 64;
    const int pb = dt & 1;
    // ---- QK^T: wave computes E[16*qh..+16)[32*kw..+32): 4 indep chains of 8
    f4v e[2][2];
    e[0][0] = e[0][1] = e[1][0] = e[1][1] = (f4v){0.f, 0.f, 0.f, 0.f};
    const short* krow = kk_ + (size_t)(d0 + 32 * kw + lr) * 512 + lk;
    #pragma unroll
    for (int ks = 0; ks < 16; ++ks) {
      s8v b0 = *(const s8v*)(krow + ks * 32);
      s8v b1 = *(const s8v*)(krow + 16 * 512 + ks * 32);
      e[0][ks >> 3] = MFMA_BF16(Qf[ks], b0, e[0][ks >> 3]);
      e[1][ks >> 3] = MFMA_BF16(Qf[ks], b1, e[1][ks >> 3]);
    }
    f4v e0 = e[0][0] + e[0][1];
    f4v e1 = e[1][0] + e[1][1];
    #pragma unroll
    for (int i = 0; i < 4; i++) {
      Es[pb][(16 * qh + lg * 4 + i) * 68 + 32 * kw + lr] = e0[i];
      Es[pb][(16 * qh + lg * 4 + i) * 68 + 32 * kw + 16 + lr] = e1[i];
    }
    // ---- V prefetch into regs (T14): in flight across both barriers
    s8v vst[16];
    #pragma unroll
    for (int nf = 0; nf < 8; ++nf) {
      const short* vrow = vt_ + (size_t)(wv * 128 + nf * 16 + lr) * 1024 + d0 + lk;
      vst[2 * nf] = *(const s8v*)vrow;
      vst[2 * nf + 1] = *(const s8v*)(vrow + 32);
    }
    asm volatile("s_waitcnt lgkmcnt(0)" ::: "memory");
    __builtin_amdgcn_s_barrier();
    // ---- online softmax (m,l in regs; row-local to this wave)
    {
      float ev[8];
      *(float4*)&ev[0] = *(const float4*)&Es[pb][r * 68 + cg * 8];
      *(float4*)&ev[4] = *(const float4*)&Es[pb][r * 68 + cg * 8 + 4];
      float tm = ev[0];
      #pragma unroll
      for (int j = 1; j < 8; j++) tm = fmaxf(tm, ev[j]);
      tm = fmaxf(tm, __shfl_xor(tm, 1));
      tm = fmaxf(tm, __shfl_xor(tm, 2));
      tm = fmaxf(tm, __shfl_xor(tm, 4));
      float mn = fmaxf(m_run, tm);
      float p[8];
      float ts = 0.f;
      #pragma unroll
      for (int j = 0; j < 8; j++) { p[j] = __expf(ev[j] - mn); ts += p[j]; }
      ts += __shfl_xor(ts, 1);
      ts += __shfl_xor(ts, 2);
      ts += __shfl_xor(ts, 4);
      float sc = __expf(m_run - mn);
      l_run = l_run * sc + ts;
      m_run = mn;
      if (cg == 0) sc_s[pb][r] = sc;
      s8v pvv;
      #pragma unroll
      for (int j = 0; j < 8; j++) pvv[j] = f2bf(p[j]);
      *(s8v*)&Ps[pb][r * 72 + cg * 8] = pvv;
    }
    asm volatile("s_waitcnt lgkmcnt(0)" ::: "memory");
    __builtin_amdgcn_s_barrier();
    // ---- rescale accumulators
    float srow[2][4];
    #pragma unroll
    for (int mi = 0; mi < 2; ++mi)
      #pragma unroll
      for (int i = 0; i < 4; ++i) srow[mi][i] = sc_s[pb][mi * 16 + lg * 4 + i];
    #pragma unroll
    for (int mi = 0; mi < 2; ++mi)
      #pragma unroll
      for (int nf = 0; nf < 8; ++nf)
        #pragma unroll
        for (int i = 0; i < 4; ++i) acc[mi][nf][i] *= srow[mi][i];
    // ---- PV from prefetched V frags
    s8v pa[2][2];
    #pragma unroll
    for (int mi = 0; mi < 2; ++mi)
      #pragma unroll
      for (int k2 = 0; k2 < 2; ++k2)
        pa[mi][k2] = *(const s8v*)&Ps[pb][(mi * 16 + lr) * 72 + k2 * 32 + lk];
    #pragma unroll
    for (int nf = 0; nf < 8; ++nf)
      #pragma unroll
      for (int k2 = 0; k2 < 2; ++k2) {
        acc[0][nf] = MFMA_BF16(pa[0][k2], vst[2 * nf + k2], acc[0][nf]);
        acc[1][nf] = MFMA_BF16(pa[1][k2], vst[2 * nf + k2], acc[1][nf]);
      }
    // no trailing barrier: E/P/sc double-buffered
  }
  if (cg == 0) l_s[r] = l_run;
  __syncthreads();
  // ---- epilogue: out = beta * (acc / l) + v
  const float beta = beta_p[0];
  const short* vres = vb + (size_t)(b * 1024 + q0) * 512;
  float invl[2][4];
  #pragma unroll
  for (int mi = 0; mi < 2; ++mi)
    #pragma unroll
    for (int i = 0; i < 4; ++i)
      invl[mi][i] = 1.0f / l_s[mi * 16 + lg * 4 + i];
  #pragma unroll
  for (int mi = 0; mi < 2; ++mi)
    #pragma unroll
    for (int nf = 0; nf < 8; ++nf)
      #pragma unroll
      for (int i = 0; i < 4; ++i) {
        int row = mi * 16 + lg * 4 + i;
        int col = wv * 128 + nf * 16 + lr;
        float val = beta * acc[mi][nf][i] * invl[mi][i] + bf2f(vres[(size_t)row * 512 + col]);
        outp[(size_t)(b * 1024 + q0 + row) * 512 + col] = val;
      }
}

extern "C" void kernel_launch(void* const* d_in, const int* in_sizes, int n_in,
                              void* d_out, int out_size, void* d_ws, size_t ws_size,
                              hipStream_t stream) {
  (void)in_sizes; (void)n_in; (void)out_size; (void)ws_size;
  const float* x = (const float*)d_in[0];
  const float* Wq = (const float*)d_in[1];
  const float* bq = (const float*)d_in[2];
  const float* Wk = (const float*)d_in[3];
  const float* bk = (const float*)d_in[4];
  const float* Wv = (const float*)d_in[5];
  const float* bv = (const float*)d_in[6];
  const float* beta = (const float*)d_in[7];
  float* out = (float*)d_out;

  char* ws = (char*)d_ws;
  short* xb = (short*)(ws);                  // reused as v_t after proj
  short* wb = (short*)(ws + 33554432);
  short* qb = (short*)(ws + 35127296);
  short* kb = (short*)(ws + 68681728);
  short* vb = (short*)(ws + 102236160);
  short* vt = xb;

  cvt_kernel<<<8192, 256, 0, stream>>>(x, xb, 2097152);
  cvt_kernel<<<128, 256, 0, stream>>>(Wq, wb, 32768);
  cvt_kernel<<<128, 256, 0, stream>>>(Wk, wb + 262144, 32768);
  cvt_kernel<<<128, 256, 0, stream>>>(Wv, wb + 524288, 32768);
  proj_kernel<<<dim3(256, 4, 3), 256, 0, stream>>>(xb, wb, bq, bk, bv, qb, kb, vb);
  transpose_kernel<<<dim3(8, 16, 32), 256, 0, stream>>>(vb, vt);
  attn_kernel<<<1024, 256, 0, stream>>>(qb, kb, vb, vt, beta, out);
}

// Round 3
// 364.496 us; speedup vs baseline: 1.3258x; 1.3191x over previous
//
#include <hip/hip_runtime.h>
#include <hip/hip_bf16.h>

typedef short s8v __attribute__((ext_vector_type(8)));   // 8 bf16 = 16B (4 VGPR)
typedef float f4v __attribute__((ext_vector_type(4)));   // MFMA accum

#define MFMA_BF16(a, b, c) __builtin_amdgcn_mfma_f32_16x16x32_bf16((a), (b), (c), 0, 0, 0)

// async global->LDS, 16B per lane; LDS dest is wave-uniform base + lane*16
#define GLDS16(g, l) __builtin_amdgcn_global_load_lds( \
    (const __attribute__((address_space(1))) void*)(g), \
    (__attribute__((address_space(3))) void*)(l), 16, 0, 0)

__device__ __forceinline__ short f2bf(float f) {
  __hip_bfloat16 h = __float2bfloat16(f);
  return *reinterpret_cast<short*>(&h);
}
__device__ __forceinline__ float bf2f(short s) {
  __hip_bfloat16 h;
  *reinterpret_cast<short*>(&h) = s;
  return __bfloat162float(h);
}

// ---------------- fp32 -> bf16 conversion (x and the three W) ----------------
__global__ __launch_bounds__(256) void cvt_kernel(const float* __restrict__ in,
                                                  short* __restrict__ out, int n8) {
  int i = blockIdx.x * 256 + threadIdx.x;
  if (i >= n8) return;
  const float* p = in + (size_t)i * 8;
  float4 a = *(const float4*)p;
  float4 b = *(const float4*)(p + 4);
  s8v o;
  o[0] = f2bf(a.x); o[1] = f2bf(a.y); o[2] = f2bf(a.z); o[3] = f2bf(a.w);
  o[4] = f2bf(b.x); o[5] = f2bf(b.y); o[6] = f2bf(b.z); o[7] = f2bf(b.w);
  *(s8v*)(out + (size_t)i * 8) = o;
}

// ---------------- projections: y = x @ W^T + b, bf16 MFMA ----------------
__global__ __launch_bounds__(256) void proj_kernel(
    const short* __restrict__ xb, const short* __restrict__ wb,
    const float* __restrict__ bq, const float* __restrict__ bk, const float* __restrict__ bv,
    short* __restrict__ qo, short* __restrict__ ko, short* __restrict__ vo) {
  const int rb = blockIdx.x;
  const int cb = blockIdx.y;
  const int mat = blockIdx.z;
  const int R0 = rb * 128, C0 = cb * 128;
  const short* w = wb + (size_t)mat * 512 * 512;
  const float* bias = (mat == 0) ? bq : (mat == 1) ? bk : bv;
  short* out = (mat == 0) ? qo : (mat == 1) ? ko : vo;

  __shared__ short xs[128 * 40];
  __shared__ short wsh[128 * 40];

  const int t = threadIdx.x;
  const int lane = t & 63, wv = t >> 6;
  const int wr = (wv >> 1) * 64, wc = (wv & 1) * 64;
  const int lr = lane & 15, lk = (lane >> 4) * 8;

  f4v acc[4][4];
  #pragma unroll
  for (int i = 0; i < 4; i++)
    #pragma unroll
    for (int j = 0; j < 4; j++) acc[i][j] = (f4v){0.f, 0.f, 0.f, 0.f};

  const int sr = t >> 1, sh = (t & 1) * 16;
  const short* xsrc = xb + (size_t)(R0 + sr) * 512 + sh;
  const short* wsrc = w + (size_t)(C0 + sr) * 512 + sh;

  for (int kk = 0; kk < 16; ++kk) {
    s8v a0 = *(const s8v*)(xsrc + kk * 32);
    s8v a1 = *(const s8v*)(xsrc + kk * 32 + 8);
    s8v b0 = *(const s8v*)(wsrc + kk * 32);
    s8v b1 = *(const s8v*)(wsrc + kk * 32 + 8);
    *(s8v*)&xs[sr * 40 + sh] = a0;
    *(s8v*)&xs[sr * 40 + sh + 8] = a1;
    *(s8v*)&wsh[sr * 40 + sh] = b0;
    *(s8v*)&wsh[sr * 40 + sh + 8] = b1;
    __syncthreads();
    s8v af[4], bf[4];
    #pragma unroll
    for (int mf = 0; mf < 4; ++mf) af[mf] = *(const s8v*)&xs[(wr + mf * 16 + lr) * 40 + lk];
    #pragma unroll
    for (int nf = 0; nf < 4; ++nf) bf[nf] = *(const s8v*)&wsh[(wc + nf * 16 + lr) * 40 + lk];
    #pragma unroll
    for (int mf = 0; mf < 4; ++mf)
      #pragma unroll
      for (int nf = 0; nf < 4; ++nf)
        acc[mf][nf] = MFMA_BF16(af[mf], bf[nf], acc[mf][nf]);
    __syncthreads();
  }
  #pragma unroll
  for (int nf = 0; nf < 4; ++nf) {
    int col = C0 + wc + nf * 16 + lr;
    float bb = bias[col];
    #pragma unroll
    for (int mf = 0; mf < 4; ++mf)
      #pragma unroll
      for (int i = 0; i < 4; i++) {
        int row = R0 + wr + mf * 16 + (lane >> 4) * 4 + i;
        out[(size_t)row * 512 + col] = f2bf(acc[mf][nf][i] + bb);
      }
  }
}

// ---------------- v (B,C,N) -> v_t (B,N,C), bf16 ----------------
__global__ __launch_bounds__(256) void transpose_kernel(const short* __restrict__ v,
                                                        short* __restrict__ vt) {
  const int nb = blockIdx.x;
  const int cbk = blockIdx.y;
  const int b = blockIdx.z;
  __shared__ short tile[64 * 72];
  const int t = threadIdx.x;
  const int r = t >> 2, qd = t & 3;
  const short* src = v + (size_t)(b * 1024 + cbk * 64 + r) * 512 + nb * 64 + qd * 16;
  s8v v0 = *(const s8v*)src;
  s8v v1 = *(const s8v*)(src + 8);
  *(s8v*)&tile[r * 72 + qd * 16] = v0;
  *(s8v*)&tile[r * 72 + qd * 16 + 8] = v1;
  __syncthreads();
  s8v o0, o1;
  #pragma unroll
  for (int j = 0; j < 8; j++) o0[j] = tile[(qd * 16 + j) * 72 + r];
  #pragma unroll
  for (int j = 0; j < 8; j++) o1[j] = tile[(qd * 16 + 8 + j) * 72 + r];
  short* dst = vt + (size_t)(b * 512 + nb * 64 + r) * 1024 + cbk * 64 + qd * 16;
  *(s8v*)dst = o0;
  *(s8v*)(dst + 8) = o1;
}

// ---------------- flash attention + beta residual (v3) ----------------
// global_load_lds pipeline: uniform 16KB chunks (4 K dim-chunks + 4 V n-chunks
// per key-block), 4-buffer ring, depth-2 staging, counted vmcnt(8), one raw
// barrier per slot. XOR swizzle (row&7)<<4 on global source + ds_read addr.
__global__ __launch_bounds__(256, 2) void attn_kernel(
    const short* __restrict__ qb, const short* __restrict__ kb,
    const short* __restrict__ vb, const short* __restrict__ vt,
    const float* __restrict__ beta_p, float* __restrict__ outp) {
  const int bx = blockIdx.x;
  const int wg = (bx & 7) * 128 + (bx >> 3);   // bijective XCD swizzle
  const int b = wg >> 5;
  const int q0 = (wg & 31) * 32;
  const int t = threadIdx.x, lane = t & 63, wv = t >> 6;
  const int lr = lane & 15, lg = lane >> 4, lk = lg * 8;

  __shared__ short stg[4][8192];   // 4 x 16KB staging ring
  __shared__ float Es[32 * 68];
  __shared__ short Ps[32 * 72];
  __shared__ float sc_s[32];
  __shared__ float l_s[32];

  const short* kb_b = kb + (size_t)b * 1024 * 512;   // [1024 keys][512 dims]
  const short* vt_b = vt + (size_t)b * 512 * 1024;   // [512 n][1024 keys]

  // Q in registers: 32 q-rows x 512 dims (A-side reuse is free)
  const short* qq = qb + (size_t)(b * 1024 + q0) * 512;
  s8v Qf[2][16];
  #pragma unroll
  for (int mi = 0; mi < 2; ++mi)
    #pragma unroll
    for (int ks = 0; ks < 16; ++ks)
      Qf[mi][ks] = *(const s8v*)(qq + (size_t)(mi * 16 + lr) * 512 + ks * 32 + lk);

  f4v acc[4][2][2];
  #pragma unroll
  for (int p = 0; p < 4; ++p)
    #pragma unroll
    for (int nf = 0; nf < 2; ++nf)
      #pragma unroll
      for (int mi = 0; mi < 2; ++mi) acc[p][nf][mi] = (f4v){0.f, 0.f, 0.f, 0.f};

  float m_run = -3.0e38f, l_run = 0.0f;
  const int r = wv * 8 + (lane >> 3);
  const int cg = lane & 7;

  // stage K dim-chunk dp of key-block dt: [64 keys][128 dims] -> 16KB
  auto stageK = [&](int dt, int dp) {
    short* dst = stg[(dt * 8 + dp) & 3];
    #pragma unroll
    for (int j = 0; j < 4; ++j) {
      int s = (4 * wv + j) * 1024 + lane * 16;   // byte within chunk
      int row = s >> 8, colb = s & 255;
      int src = colb ^ ((row & 7) << 4);         // inverse-swizzled source
      GLDS16((const char*)(kb_b + (size_t)(dt * 64 + row) * 512 + dp * 128) + src,
             (char*)dst + (4 * wv + j) * 1024);
    }
  };
  // stage V n-chunk np of key-block dt: [128 n][64 keys] -> 16KB
  auto stageV = [&](int dt, int np) {
    short* dst = stg[(dt * 8 + 4 + np) & 3];
    #pragma unroll
    for (int j = 0; j < 4; ++j) {
      int s = (4 * wv + j) * 1024 + lane * 16;
      int row = s >> 7, colb = s & 127;
      int src = colb ^ ((row & 7) << 4);
      GLDS16((const char*)(vt_b + (size_t)(np * 128 + row) * 1024 + dt * 64) + src,
             (char*)dst + (4 * wv + j) * 1024);
    }
  };
  auto stage_c = [&](int c) {   // c = global chunk index (8 per key-block)
    int dt = c >> 3, cc = c & 7;
    if (dt >= 16) return;
    if (cc < 4) stageK(dt, cc); else stageV(dt, cc - 4);
  };

  stage_c(0);
  stage_c(1);

  for (int dt = 0; dt < 16; ++dt) {
    f4v e0 = (f4v){0.f, 0.f, 0.f, 0.f};
    f4v e1 = (f4v){0.f, 0.f, 0.f, 0.f};
    // ---- 4 K slots: QK^T over 128-dim chunks; wave owns 16 keys [16*wv..)
    #pragma unroll
    for (int dp = 0; dp < 4; ++dp) {
      stage_c(8 * dt + dp + 2);
      asm volatile("s_waitcnt vmcnt(8)" ::: "memory");
      __builtin_amdgcn_s_barrier();
      asm volatile("" ::: "memory");
      const char* kc = (const char*)stg[(8 * dt + dp) & 3];
      #pragma unroll
      for (int q = 0; q < 4; ++q) {
        s8v kf = *(const s8v*)(kc + (16 * wv + lr) * 256 +
                               ((q * 64 + lg * 16) ^ ((lr & 7) << 4)));
        e0 = MFMA_BF16(Qf[0][dp * 4 + q], kf, e0);
        e1 = MFMA_BF16(Qf[1][dp * 4 + q], kf, e1);
      }
    }
    // ---- store E tile (rows = q, cols = key 16*wv+lr)
    #pragma unroll
    for (int i = 0; i < 4; ++i) {
      Es[(lg * 4 + i) * 68 + 16 * wv + lr] = e0[i];
      Es[(16 + lg * 4 + i) * 68 + 16 * wv + lr] = e1[i];
    }
    asm volatile("s_waitcnt lgkmcnt(0)" ::: "memory");
    __builtin_amdgcn_s_barrier();
    asm volatile("" ::: "memory");
    // ---- SM slot: online softmax (8 lanes/row x 8 cols)
    {
      float ev[8];
      *(float4*)&ev[0] = *(const float4*)&Es[r * 68 + cg * 8];
      *(float4*)&ev[4] = *(const float4*)&Es[r * 68 + cg * 8 + 4];
      float tm = ev[0];
      #pragma unroll
      for (int j = 1; j < 8; j++) tm = fmaxf(tm, ev[j]);
      tm = fmaxf(tm, __shfl_xor(tm, 1));
      tm = fmaxf(tm, __shfl_xor(tm, 2));
      tm = fmaxf(tm, __shfl_xor(tm, 4));
      float mn = fmaxf(m_run, tm);
      float p[8];
      float ts = 0.f;
      #pragma unroll
      for (int j = 0; j < 8; j++) { p[j] = __expf(ev[j] - mn); ts += p[j]; }
      ts += __shfl_xor(ts, 1);
      ts += __shfl_xor(ts, 2);
      ts += __shfl_xor(ts, 4);
      float sc = __expf(m_run - mn);
      l_run = l_run * sc + ts;
      m_run = mn;
      if (cg == 0) sc_s[r] = sc;
      s8v pvv;
      #pragma unroll
      for (int j = 0; j < 8; j++) pvv[j] = f2bf(p[j]);
      *(s8v*)&Ps[r * 72 + cg * 8] = pvv;
    }
    // ---- 4 V slots: PV over 128-n chunks; wave owns 32 n within each chunk
    s8v pa[2][2];
    #pragma unroll
    for (int np = 0; np < 4; ++np) {
      stage_c(8 * dt + 4 + np + 2);
      if (dt == 15 && np == 2) {
        asm volatile("s_waitcnt vmcnt(4)" ::: "memory");
      } else if (dt == 15 && np == 3) {
        asm volatile("s_waitcnt vmcnt(0)" ::: "memory");
      } else {
        asm volatile("s_waitcnt vmcnt(8)" ::: "memory");
      }
      if (np == 0) asm volatile("s_waitcnt lgkmcnt(0)" ::: "memory");
      __builtin_amdgcn_s_barrier();
      asm volatile("" ::: "memory");
      if (np == 0) {
        // rescale all accumulators once per key-block; load P fragments
        float srow[2][4];
        #pragma unroll
        for (int mi = 0; mi < 2; ++mi)
          #pragma unroll
          for (int i = 0; i < 4; ++i) srow[mi][i] = sc_s[mi * 16 + lg * 4 + i];
        #pragma unroll
        for (int p = 0; p < 4; ++p)
          #pragma unroll
          for (int nf = 0; nf < 2; ++nf)
            #pragma unroll
            for (int mi = 0; mi < 2; ++mi)
              #pragma unroll
              for (int i = 0; i < 4; ++i) acc[p][nf][mi][i] *= srow[mi][i];
        #pragma unroll
        for (int mi = 0; mi < 2; ++mi)
          #pragma unroll
          for (int k2 = 0; k2 < 2; ++k2)
            pa[mi][k2] = *(const s8v*)&Ps[(mi * 16 + lr) * 72 + k2 * 32 + lk];
      }
      const char* vc = (const char*)stg[(8 * dt + 4 + np) & 3];
      #pragma unroll
      for (int nf = 0; nf < 2; ++nf)
        #pragma unroll
        for (int k2 = 0; k2 < 2; ++k2) {
          s8v vf = *(const s8v*)(vc + (32 * wv + nf * 16 + lr) * 128 +
                                 ((k2 * 64 + lg * 16) ^ ((lr & 7) << 4)));
          acc[np][nf][0] = MFMA_BF16(pa[0][k2], vf, acc[np][nf][0]);
          acc[np][nf][1] = MFMA_BF16(pa[1][k2], vf, acc[np][nf][1]);
        }
    }
  }
  if (cg == 0) l_s[r] = l_run;
  __syncthreads();
  // ---- epilogue: out = beta * (acc / l) + v
  const float beta = beta_p[0];
  const short* vres = vb + (size_t)(b * 1024 + q0) * 512;
  float invl[2][4];
  #pragma unroll
  for (int mi = 0; mi < 2; ++mi)
    #pragma unroll
    for (int i = 0; i < 4; ++i)
      invl[mi][i] = 1.0f / l_s[mi * 16 + lg * 4 + i];
  #pragma unroll
  for (int p = 0; p < 4; ++p)
    #pragma unroll
    for (int nf = 0; nf < 2; ++nf)
      #pragma unroll
      for (int mi = 0; mi < 2; ++mi)
        #pragma unroll
        for (int i = 0; i < 4; ++i) {
          int row = mi * 16 + lg * 4 + i;
          int col = p * 128 + wv * 32 + nf * 16 + lr;
          float val = beta * acc[p][nf][mi][i] * invl[mi][i] +
                      bf2f(vres[(size_t)row * 512 + col]);
          outp[(size_t)(b * 1024 + q0 + row) * 512 + col] = val;
        }
}

extern "C" void kernel_launch(void* const* d_in, const int* in_sizes, int n_in,
                              void* d_out, int out_size, void* d_ws, size_t ws_size,
                              hipStream_t stream) {
  (void)in_sizes; (void)n_in; (void)out_size; (void)ws_size;
  const float* x = (const float*)d_in[0];
  const float* Wq = (const float*)d_in[1];
  const float* bq = (const float*)d_in[2];
  const float* Wk = (const float*)d_in[3];
  const float* bk = (const float*)d_in[4];
  const float* Wv = (const float*)d_in[5];
  const float* bv = (const float*)d_in[6];
  const float* beta = (const float*)d_in[7];
  float* out = (float*)d_out;

  char* ws = (char*)d_ws;
  short* xb = (short*)(ws);                  // reused as v_t after proj
  short* wb = (short*)(ws + 33554432);
  short* qb = (short*)(ws + 35127296);
  short* kb = (short*)(ws + 68681728);
  short* vb = (short*)(ws + 102236160);
  short* vt = xb;

  cvt_kernel<<<8192, 256, 0, stream>>>(x, xb, 2097152);
  cvt_kernel<<<128, 256, 0, stream>>>(Wq, wb, 32768);
  cvt_kernel<<<128, 256, 0, stream>>>(Wk, wb + 262144, 32768);
  cvt_kernel<<<128, 256, 0, stream>>>(Wv, wb + 524288, 32768);
  proj_kernel<<<dim3(256, 4, 3), 256, 0, stream>>>(xb, wb, bq, bk, bv, qb, kb, vb);
  transpose_kernel<<<dim3(8, 16, 32), 256, 0, stream>>>(vb, vt);
  attn_kernel<<<1024, 256, 0, stream>>>(qb, kb, vb, vt, beta, out);
}

// Round 4
// 295.164 us; speedup vs baseline: 1.6372x; 1.2349x over previous
//
#include <hip/hip_runtime.h>
#include <hip/hip_bf16.h>

typedef short s8v __attribute__((ext_vector_type(8)));   // 8 bf16 = 16B (4 VGPR)
typedef float f4v __attribute__((ext_vector_type(4)));   // MFMA accum

#define MFMA_BF16(a, b, c) __builtin_amdgcn_mfma_f32_16x16x32_bf16((a), (b), (c), 0, 0, 0)

__device__ __forceinline__ short f2bf(float f) {
  __hip_bfloat16 h = __float2bfloat16(f);
  return *reinterpret_cast<short*>(&h);
}
__device__ __forceinline__ float bf2f(short s) {
  __hip_bfloat16 h;
  *reinterpret_cast<short*>(&h) = s;
  return __bfloat162float(h);
}

// ---------------- fp32 -> bf16 conversion (x and the three W) ----------------
__global__ __launch_bounds__(256) void cvt_kernel(const float* __restrict__ in,
                                                  short* __restrict__ out, int n8) {
  int i = blockIdx.x * 256 + threadIdx.x;
  if (i >= n8) return;
  const float* p = in + (size_t)i * 8;
  float4 a = *(const float4*)p;
  float4 b = *(const float4*)(p + 4);
  s8v o;
  o[0] = f2bf(a.x); o[1] = f2bf(a.y); o[2] = f2bf(a.z); o[3] = f2bf(a.w);
  o[4] = f2bf(b.x); o[5] = f2bf(b.y); o[6] = f2bf(b.z); o[7] = f2bf(b.w);
  *(s8v*)(out + (size_t)i * 8) = o;
}

// ---------------- projections: y = x @ W^T + b, bf16 MFMA ----------------
__global__ __launch_bounds__(256) void proj_kernel(
    const short* __restrict__ xb, const short* __restrict__ wb,
    const float* __restrict__ bq, const float* __restrict__ bk, const float* __restrict__ bv,
    short* __restrict__ qo, short* __restrict__ ko, short* __restrict__ vo) {
  const int rb = blockIdx.x;
  const int cb = blockIdx.y;
  const int mat = blockIdx.z;
  const int R0 = rb * 128, C0 = cb * 128;
  const short* w = wb + (size_t)mat * 512 * 512;
  const float* bias = (mat == 0) ? bq : (mat == 1) ? bk : bv;
  short* out = (mat == 0) ? qo : (mat == 1) ? ko : vo;

  __shared__ short xs[128 * 40];
  __shared__ short wsh[128 * 40];

  const int t = threadIdx.x;
  const int lane = t & 63, wv = t >> 6;
  const int wr = (wv >> 1) * 64, wc = (wv & 1) * 64;
  const int lr = lane & 15, lk = (lane >> 4) * 8;

  f4v acc[4][4];
  #pragma unroll
  for (int i = 0; i < 4; i++)
    #pragma unroll
    for (int j = 0; j < 4; j++) acc[i][j] = (f4v){0.f, 0.f, 0.f, 0.f};

  const int sr = t >> 1, sh = (t & 1) * 16;
  const short* xsrc = xb + (size_t)(R0 + sr) * 512 + sh;
  const short* wsrc = w + (size_t)(C0 + sr) * 512 + sh;

  for (int kk = 0; kk < 16; ++kk) {
    s8v a0 = *(const s8v*)(xsrc + kk * 32);
    s8v a1 = *(const s8v*)(xsrc + kk * 32 + 8);
    s8v b0 = *(const s8v*)(wsrc + kk * 32);
    s8v b1 = *(const s8v*)(wsrc + kk * 32 + 8);
    *(s8v*)&xs[sr * 40 + sh] = a0;
    *(s8v*)&xs[sr * 40 + sh + 8] = a1;
    *(s8v*)&wsh[sr * 40 + sh] = b0;
    *(s8v*)&wsh[sr * 40 + sh + 8] = b1;
    __syncthreads();
    s8v af[4], bf[4];
    #pragma unroll
    for (int mf = 0; mf < 4; ++mf) af[mf] = *(const s8v*)&xs[(wr + mf * 16 + lr) * 40 + lk];
    #pragma unroll
    for (int nf = 0; nf < 4; ++nf) bf[nf] = *(const s8v*)&wsh[(wc + nf * 16 + lr) * 40 + lk];
    #pragma unroll
    for (int mf = 0; mf < 4; ++mf)
      #pragma unroll
      for (int nf = 0; nf < 4; ++nf)
        acc[mf][nf] = MFMA_BF16(af[mf], bf[nf], acc[mf][nf]);
    __syncthreads();
  }
  #pragma unroll
  for (int nf = 0; nf < 4; ++nf) {
    int col = C0 + wc + nf * 16 + lr;
    float bb = bias[col];
    #pragma unroll
    for (int mf = 0; mf < 4; ++mf)
      #pragma unroll
      for (int i = 0; i < 4; i++) {
        int row = R0 + wr + mf * 16 + (lane >> 4) * 4 + i;
        out[(size_t)row * 512 + col] = f2bf(acc[mf][nf][i] + bb);
      }
  }
}

// ---------------- v (B,C,N) -> v_t (B,N,C), bf16 ----------------
__global__ __launch_bounds__(256) void transpose_kernel(const short* __restrict__ v,
                                                        short* __restrict__ vt) {
  const int nb = blockIdx.x;
  const int cbk = blockIdx.y;
  const int b = blockIdx.z;
  __shared__ short tile[64 * 72];
  const int t = threadIdx.x;
  const int r = t >> 2, qd = t & 3;
  const short* src = v + (size_t)(b * 1024 + cbk * 64 + r) * 512 + nb * 64 + qd * 16;
  s8v v0 = *(const s8v*)src;
  s8v v1 = *(const s8v*)(src + 8);
  *(s8v*)&tile[r * 72 + qd * 16] = v0;
  *(s8v*)&tile[r * 72 + qd * 16 + 8] = v1;
  __syncthreads();
  s8v o0, o1;
  #pragma unroll
  for (int j = 0; j < 8; j++) o0[j] = tile[(qd * 16 + j) * 72 + r];
  #pragma unroll
  for (int j = 0; j < 8; j++) o1[j] = tile[(qd * 16 + 8 + j) * 72 + r];
  short* dst = vt + (size_t)(b * 512 + nb * 64 + r) * 1024 + cbk * 64 + qd * 16;
  *(s8v*)dst = o0;
  *(s8v*)(dst + 8) = o1;
}

// ---------------- E = Q @ K^T per batch (M=N=1024, K=512), out bf16 ----------
__global__ __launch_bounds__(256) void qk_kernel(const short* __restrict__ qb,
                                                 const short* __restrict__ kb,
                                                 short* __restrict__ eb) {
  const int rb = blockIdx.x;   // 0..7
  const int cb = blockIdx.y;   // 0..7
  const int b = blockIdx.z;    // 0..31
  const int R0 = rb * 128, C0 = cb * 128;

  __shared__ short xs[128 * 40];
  __shared__ short wsh[128 * 40];

  const int t = threadIdx.x;
  const int lane = t & 63, wv = t >> 6;
  const int wr = (wv >> 1) * 64, wc = (wv & 1) * 64;
  const int lr = lane & 15, lk = (lane >> 4) * 8;

  f4v acc[4][4];
  #pragma unroll
  for (int i = 0; i < 4; i++)
    #pragma unroll
    for (int j = 0; j < 4; j++) acc[i][j] = (f4v){0.f, 0.f, 0.f, 0.f};

  const int sr = t >> 1, sh = (t & 1) * 16;
  const short* asrc = qb + (size_t)(b * 1024 + R0 + sr) * 512 + sh;
  const short* bsrc = kb + (size_t)(b * 1024 + C0 + sr) * 512 + sh;

  for (int kk = 0; kk < 16; ++kk) {
    s8v a0 = *(const s8v*)(asrc + kk * 32);
    s8v a1 = *(const s8v*)(asrc + kk * 32 + 8);
    s8v b0 = *(const s8v*)(bsrc + kk * 32);
    s8v b1 = *(const s8v*)(bsrc + kk * 32 + 8);
    *(s8v*)&xs[sr * 40 + sh] = a0;
    *(s8v*)&xs[sr * 40 + sh + 8] = a1;
    *(s8v*)&wsh[sr * 40 + sh] = b0;
    *(s8v*)&wsh[sr * 40 + sh + 8] = b1;
    __syncthreads();
    s8v af[4], bf[4];
    #pragma unroll
    for (int mf = 0; mf < 4; ++mf) af[mf] = *(const s8v*)&xs[(wr + mf * 16 + lr) * 40 + lk];
    #pragma unroll
    for (int nf = 0; nf < 4; ++nf) bf[nf] = *(const s8v*)&wsh[(wc + nf * 16 + lr) * 40 + lk];
    #pragma unroll
    for (int mf = 0; mf < 4; ++mf)
      #pragma unroll
      for (int nf = 0; nf < 4; ++nf)
        acc[mf][nf] = MFMA_BF16(af[mf], bf[nf], acc[mf][nf]);
    __syncthreads();
  }
  #pragma unroll
  for (int nf = 0; nf < 4; ++nf) {
    int col = C0 + wc + nf * 16 + lr;
    #pragma unroll
    for (int mf = 0; mf < 4; ++mf)
      #pragma unroll
      for (int i = 0; i < 4; i++) {
        int row = R0 + wr + mf * 16 + (lane >> 4) * 4 + i;
        eb[(size_t)(b * 1024 + row) * 1024 + col] = f2bf(acc[mf][nf][i]);
      }
  }
}

// ---------------- in-place row softmax on E (rows of 1024 bf16) -------------
// one wave per row; lane holds 16 elements in registers
__global__ __launch_bounds__(256) void softmax_kernel(short* __restrict__ eb) {
  const int row = blockIdx.x * 4 + (threadIdx.x >> 6);
  const int lane = threadIdx.x & 63;
  short* p = eb + (size_t)row * 1024 + lane * 16;
  s8v a = *(const s8v*)p;
  s8v bvv = *(const s8v*)(p + 8);
  float v[16];
  #pragma unroll
  for (int j = 0; j < 8; j++) { v[j] = bf2f(a[j]); v[8 + j] = bf2f(bvv[j]); }
  float m = v[0];
  #pragma unroll
  for (int j = 1; j < 16; j++) m = fmaxf(m, v[j]);
  #pragma unroll
  for (int s = 1; s <= 32; s <<= 1) m = fmaxf(m, __shfl_xor(m, s));
  float l = 0.f;
  #pragma unroll
  for (int j = 0; j < 16; j++) { v[j] = __expf(v[j] - m); l += v[j]; }
  #pragma unroll
  for (int s = 1; s <= 32; s <<= 1) l += __shfl_xor(l, s);
  const float inv = 1.0f / l;
  s8v o0, o1;
  #pragma unroll
  for (int j = 0; j < 8; j++) { o0[j] = f2bf(v[j] * inv); o1[j] = f2bf(v[8 + j] * inv); }
  *(s8v*)p = o0;
  *(s8v*)(p + 8) = o1;
}

// ---------------- out = beta * (P @ V) + v  (per batch M=1024,N=512,K=1024) --
// A = P (eb, normalized bf16), B = vt [n][keys] (so B-frag rows are contiguous)
__global__ __launch_bounds__(256) void pv_kernel(const short* __restrict__ eb,
                                                 const short* __restrict__ vt,
                                                 const short* __restrict__ vb,
                                                 const float* __restrict__ beta_p,
                                                 float* __restrict__ outp) {
  const int rb = blockIdx.x;   // 0..7
  const int cb = blockIdx.y;   // 0..3
  const int b = blockIdx.z;    // 0..31
  const int R0 = rb * 128, C0 = cb * 128;

  __shared__ short xs[128 * 40];
  __shared__ short wsh[128 * 40];

  const int t = threadIdx.x;
  const int lane = t & 63, wv = t >> 6;
  const int wr = (wv >> 1) * 64, wc = (wv & 1) * 64;
  const int lr = lane & 15, lk = (lane >> 4) * 8;

  f4v acc[4][4];
  #pragma unroll
  for (int i = 0; i < 4; i++)
    #pragma unroll
    for (int j = 0; j < 4; j++) acc[i][j] = (f4v){0.f, 0.f, 0.f, 0.f};

  const int sr = t >> 1, sh = (t & 1) * 16;
  const short* asrc = eb + (size_t)(b * 1024 + R0 + sr) * 1024 + sh;
  const short* bsrc = vt + (size_t)(b * 512 + C0 + sr) * 1024 + sh;

  for (int kk = 0; kk < 32; ++kk) {
    s8v a0 = *(const s8v*)(asrc + kk * 32);
    s8v a1 = *(const s8v*)(asrc + kk * 32 + 8);
    s8v b0 = *(const s8v*)(bsrc + kk * 32);
    s8v b1 = *(const s8v*)(bsrc + kk * 32 + 8);
    *(s8v*)&xs[sr * 40 + sh] = a0;
    *(s8v*)&xs[sr * 40 + sh + 8] = a1;
    *(s8v*)&wsh[sr * 40 + sh] = b0;
    *(s8v*)&wsh[sr * 40 + sh + 8] = b1;
    __syncthreads();
    s8v af[4], bf[4];
    #pragma unroll
    for (int mf = 0; mf < 4; ++mf) af[mf] = *(const s8v*)&xs[(wr + mf * 16 + lr) * 40 + lk];
    #pragma unroll
    for (int nf = 0; nf < 4; ++nf) bf[nf] = *(const s8v*)&wsh[(wc + nf * 16 + lr) * 40 + lk];
    #pragma unroll
    for (int mf = 0; mf < 4; ++mf)
      #pragma unroll
      for (int nf = 0; nf < 4; ++nf)
        acc[mf][nf] = MFMA_BF16(af[mf], bf[nf], acc[mf][nf]);
    __syncthreads();
  }
  const float beta = beta_p[0];
  #pragma unroll
  for (int nf = 0; nf < 4; ++nf) {
    int col = C0 + wc + nf * 16 + lr;
    #pragma unroll
    for (int mf = 0; mf < 4; ++mf)
      #pragma unroll
      for (int i = 0; i < 4; i++) {
        int row = R0 + wr + mf * 16 + (lane >> 4) * 4 + i;
        float val = beta * acc[mf][nf][i] +
                    bf2f(vb[(size_t)(b * 1024 + row) * 512 + col]);
        outp[(size_t)(b * 1024 + row) * 512 + col] = val;
      }
  }
}

extern "C" void kernel_launch(void* const* d_in, const int* in_sizes, int n_in,
                              void* d_out, int out_size, void* d_ws, size_t ws_size,
                              hipStream_t stream) {
  (void)in_sizes; (void)n_in; (void)out_size; (void)ws_size;
  const float* x = (const float*)d_in[0];
  const float* Wq = (const float*)d_in[1];
  const float* bq = (const float*)d_in[2];
  const float* Wk = (const float*)d_in[3];
  const float* bk = (const float*)d_in[4];
  const float* Wv = (const float*)d_in[5];
  const float* bv = (const float*)d_in[6];
  const float* beta = (const float*)d_in[7];
  float* out = (float*)d_out;

  char* ws = (char*)d_ws;
  short* xb = (short*)(ws);                  // 32MB, reused as v_t after proj
  short* wb = (short*)(ws + 33554432);       // 1.5MB
  short* qb = (short*)(ws + 35127296);       // 32MB
  short* kb = (short*)(ws + 68681728);       // 32MB
  short* vb = (short*)(ws + 102236160);      // 32MB
  short* eb = (short*)(ws + 135790592);      // 64MB (E, then P in-place)
  short* vt = xb;

  cvt_kernel<<<8192, 256, 0, stream>>>(x, xb, 2097152);
  cvt_kernel<<<128, 256, 0, stream>>>(Wq, wb, 32768);
  cvt_kernel<<<128, 256, 0, stream>>>(Wk, wb + 262144, 32768);
  cvt_kernel<<<128, 256, 0, stream>>>(Wv, wb + 524288, 32768);
  proj_kernel<<<dim3(256, 4, 3), 256, 0, stream>>>(xb, wb, bq, bk, bv, qb, kb, vb);
  transpose_kernel<<<dim3(8, 16, 32), 256, 0, stream>>>(vb, vt);
  qk_kernel<<<dim3(8, 8, 32), 256, 0, stream>>>(qb, kb, eb);
  softmax_kernel<<<8192, 256, 0, stream>>>(eb);
  pv_kernel<<<dim3(8, 4, 32), 256, 0, stream>>>(eb, vt, vb, beta, out);
}

// Round 5
// 236.756 us; speedup vs baseline: 2.0411x; 1.2467x over previous
//
#include <hip/hip_runtime.h>
#include <hip/hip_bf16.h>

typedef short s8v __attribute__((ext_vector_type(8)));   // 8 bf16 = 16B (4 VGPR)
typedef float f4v __attribute__((ext_vector_type(4)));   // MFMA accum

#define MFMA_BF16(a, b, c) __builtin_amdgcn_mfma_f32_16x16x32_bf16((a), (b), (c), 0, 0, 0)

// async global->LDS, 16B per lane; LDS dest = wave-uniform base + lane*16
#define GLDS16(g, l) __builtin_amdgcn_global_load_lds( \
    (const __attribute__((address_space(1))) void*)(g), \
    (__attribute__((address_space(3))) void*)(l), 16, 0, 0)

__device__ __forceinline__ short f2bf(float f) {
  __hip_bfloat16 h = __float2bfloat16(f);
  return *reinterpret_cast<short*>(&h);
}
__device__ __forceinline__ float bf2f(short s) {
  __hip_bfloat16 h;
  *reinterpret_cast<short*>(&h) = s;
  return __bfloat162float(h);
}

// ---------------- fp32 -> bf16 conversion ----------------
__global__ __launch_bounds__(256) void cvt_kernel(const float* __restrict__ in,
                                                  short* __restrict__ out, int n8) {
  int i = blockIdx.x * 256 + threadIdx.x;
  if (i >= n8) return;
  const float* p = in + (size_t)i * 8;
  float4 a = *(const float4*)p;
  float4 b = *(const float4*)(p + 4);
  s8v o;
  o[0] = f2bf(a.x); o[1] = f2bf(a.y); o[2] = f2bf(a.z); o[3] = f2bf(a.w);
  o[4] = f2bf(b.x); o[5] = f2bf(b.y); o[6] = f2bf(b.z); o[7] = f2bf(b.w);
  *(s8v*)(out + (size_t)i * 8) = o;
}

// ---------------- m97-style GEMM core: 128x128 tile, BK=64 ----------------
// A row-major [M][ASTR] over K; B row-major [N][BSTR] over K (B^T layout).
// LDS linear [128][64] shorts per matrix; XOR swizzle (row&7)<<4 applied to
// the per-lane GLOBAL source byte-offset AND the ds_read address (rule 21).
template<int KSTEPS, int ASTR, int BSTR>
__device__ __forceinline__ void mm_core(const short* __restrict__ Abase,
                                        const short* __restrict__ Bbase,
                                        short* As, short* Bs, f4v (&acc)[4][4]) {
  const int t = threadIdx.x;
  const int lane = t & 63, w = t >> 6;
  const int lr = lane & 15, lg = lane >> 4;
  const int wr = (w >> 1) * 64, wc = (w & 1) * 64;
  const int srcc = ((lane & 7) * 16) ^ ((lane >> 3) << 4);  // swizzled src col byte
  const int rstage = w * 32 + (lane >> 3);                  // staging row (j adds 8)

  for (int kt = 0; kt < KSTEPS; ++kt) {
    #pragma unroll
    for (int j = 0; j < 4; ++j)
      GLDS16((const char*)(Abase + (size_t)(rstage + j * 8) * ASTR) + kt * 128 + srcc,
             (char*)As + (w * 32 + j * 8) * 128);
    #pragma unroll
    for (int j = 0; j < 4; ++j)
      GLDS16((const char*)(Bbase + (size_t)(rstage + j * 8) * BSTR) + kt * 128 + srcc,
             (char*)Bs + (w * 32 + j * 8) * 128);
    __syncthreads();   // compiler drains vmcnt(0) before s_barrier: tiles ready
    #pragma unroll
    for (int kk = 0; kk < 2; ++kk) {
      s8v af[4], bfr[4];
      #pragma unroll
      for (int mf = 0; mf < 4; ++mf)
        af[mf] = *(const s8v*)((const char*)As + (wr + mf * 16 + lr) * 128 +
                               ((kk * 64 + lg * 16) ^ ((lr & 7) << 4)));
      #pragma unroll
      for (int nf = 0; nf < 4; ++nf)
        bfr[nf] = *(const s8v*)((const char*)Bs + (wc + nf * 16 + lr) * 128 +
                                ((kk * 64 + lg * 16) ^ ((lr & 7) << 4)));
      #pragma unroll
      for (int mf = 0; mf < 4; ++mf)
        #pragma unroll
        for (int nf = 0; nf < 4; ++nf)
          acc[mf][nf] = MFMA_BF16(af[mf], bfr[nf], acc[mf][nf]);
    }
    __syncthreads();   // done reading; next kt overwrites
  }
}

// ---------------- projections: y = x @ W^T + b ----------------
__global__ __launch_bounds__(256) void proj_kernel(
    const short* __restrict__ xb, const short* __restrict__ wb,
    const float* __restrict__ bq, const float* __restrict__ bk, const float* __restrict__ bv,
    short* __restrict__ qo, short* __restrict__ ko, short* __restrict__ vo) {
  const int bx = blockIdx.x;
  const int L = (bx & 7) * 384 + (bx >> 3);   // bijective XCD swizzle (3072 = 8*384)
  const int cb = L & 3, rb = (L >> 2) & 255, mat = L >> 10;
  const int R0 = rb * 128, C0 = cb * 128;
  const float* bias = (mat == 0) ? bq : (mat == 1) ? bk : bv;
  short* out = (mat == 0) ? qo : (mat == 1) ? ko : vo;

  __shared__ short As[8192], Bs[8192];
  f4v acc[4][4];
  #pragma unroll
  for (int i = 0; i < 4; i++)
    #pragma unroll
    for (int j = 0; j < 4; j++) acc[i][j] = (f4v){0.f, 0.f, 0.f, 0.f};

  mm_core<8, 512, 512>(xb + (size_t)R0 * 512,
                       wb + (size_t)mat * 512 * 512 + (size_t)C0 * 512, As, Bs, acc);

  const int lane = threadIdx.x & 63, w = threadIdx.x >> 6;
  const int lr = lane & 15, lg = lane >> 4;
  const int wr = (w >> 1) * 64, wc = (w & 1) * 64;
  #pragma unroll
  for (int nf = 0; nf < 4; ++nf) {
    int col = C0 + wc + nf * 16 + lr;
    float bb = bias[col];
    #pragma unroll
    for (int mf = 0; mf < 4; ++mf)
      #pragma unroll
      for (int i = 0; i < 4; i++) {
        int row = R0 + wr + mf * 16 + lg * 4 + i;
        out[(size_t)row * 512 + col] = f2bf(acc[mf][nf][i] + bb);
      }
  }
}

// ---------------- v (B,C,N) -> v_t (B,N,C) ----------------
__global__ __launch_bounds__(256) void transpose_kernel(const short* __restrict__ v,
                                                        short* __restrict__ vt) {
  const int nb = blockIdx.x;
  const int cbk = blockIdx.y;
  const int b = blockIdx.z;
  __shared__ short tile[64 * 72];
  const int t = threadIdx.x;
  const int r = t >> 2, qd = t & 3;
  const short* src = v + (size_t)(b * 1024 + cbk * 64 + r) * 512 + nb * 64 + qd * 16;
  s8v v0 = *(const s8v*)src;
  s8v v1 = *(const s8v*)(src + 8);
  *(s8v*)&tile[r * 72 + qd * 16] = v0;
  *(s8v*)&tile[r * 72 + qd * 16 + 8] = v1;
  __syncthreads();
  s8v o0, o1;
  #pragma unroll
  for (int j = 0; j < 8; j++) o0[j] = tile[(qd * 16 + j) * 72 + r];
  #pragma unroll
  for (int j = 0; j < 8; j++) o1[j] = tile[(qd * 16 + 8 + j) * 72 + r];
  short* dst = vt + (size_t)(b * 512 + nb * 64 + r) * 1024 + cbk * 64 + qd * 16;
  *(s8v*)dst = o0;
  *(s8v*)(dst + 8) = o1;
}

// ---------------- E = Q @ K^T per batch ----------------
__global__ __launch_bounds__(256) void qk_kernel(const short* __restrict__ qb,
                                                 const short* __restrict__ kb,
                                                 short* __restrict__ eb) {
  const int bx = blockIdx.x;
  const int L = (bx & 7) * 256 + (bx >> 3);   // 2048 = 8*256
  const int rb = L & 7, cb = (L >> 3) & 7, b = L >> 6;
  const int R0 = rb * 128, C0 = cb * 128;

  __shared__ short As[8192], Bs[8192];
  f4v acc[4][4];
  #pragma unroll
  for (int i = 0; i < 4; i++)
    #pragma unroll
    for (int j = 0; j < 4; j++) acc[i][j] = (f4v){0.f, 0.f, 0.f, 0.f};

  mm_core<8, 512, 512>(qb + (size_t)(b * 1024 + R0) * 512,
                       kb + (size_t)(b * 1024 + C0) * 512, As, Bs, acc);

  const int lane = threadIdx.x & 63, w = threadIdx.x >> 6;
  const int lr = lane & 15, lg = lane >> 4;
  const int wr = (w >> 1) * 64, wc = (w & 1) * 64;
  #pragma unroll
  for (int nf = 0; nf < 4; ++nf) {
    int col = C0 + wc + nf * 16 + lr;
    #pragma unroll
    for (int mf = 0; mf < 4; ++mf)
      #pragma unroll
      for (int i = 0; i < 4; i++) {
        int row = R0 + wr + mf * 16 + lg * 4 + i;
        eb[(size_t)(b * 1024 + row) * 1024 + col] = f2bf(acc[mf][nf][i]);
      }
  }
}

// ---------------- in-place row softmax (rows of 1024 bf16) ----------------
__global__ __launch_bounds__(256) void softmax_kernel(short* __restrict__ eb) {
  const int row = blockIdx.x * 4 + (threadIdx.x >> 6);
  const int lane = threadIdx.x & 63;
  short* p = eb + (size_t)row * 1024 + lane * 16;
  s8v a = *(const s8v*)p;
  s8v bvv = *(const s8v*)(p + 8);
  float v[16];
  #pragma unroll
  for (int j = 0; j < 8; j++) { v[j] = bf2f(a[j]); v[8 + j] = bf2f(bvv[j]); }
  float m = v[0];
  #pragma unroll
  for (int j = 1; j < 16; j++) m = fmaxf(m, v[j]);
  #pragma unroll
  for (int s = 1; s <= 32; s <<= 1) m = fmaxf(m, __shfl_xor(m, s));
  float l = 0.f;
  #pragma unroll
  for (int j = 0; j < 16; j++) { v[j] = __expf(v[j] - m); l += v[j]; }
  #pragma unroll
  for (int s = 1; s <= 32; s <<= 1) l += __shfl_xor(l, s);
  const float inv = 1.0f / l;
  s8v o0, o1;
  #pragma unroll
  for (int j = 0; j < 8; j++) { o0[j] = f2bf(v[j] * inv); o1[j] = f2bf(v[8 + j] * inv); }
  *(s8v*)p = o0;
  *(s8v*)(p + 8) = o1;
}

// ---------------- out = beta * (P @ V) + v ----------------
__global__ __launch_bounds__(256) void pv_kernel(const short* __restrict__ eb,
                                                 const short* __restrict__ vt,
                                                 const short* __restrict__ vb,
                                                 const float* __restrict__ beta_p,
                                                 float* __restrict__ outp) {
  const int bx = blockIdx.x;
  const int L = (bx & 7) * 128 + (bx >> 3);   // 1024 = 8*128
  const int cb = L & 3, rb = (L >> 2) & 7, b = L >> 5;
  const int R0 = rb * 128, C0 = cb * 128;

  __shared__ short As[8192], Bs[8192];
  f4v acc[4][4];
  #pragma unroll
  for (int i = 0; i < 4; i++)
    #pragma unroll
    for (int j = 0; j < 4; j++) acc[i][j] = (f4v){0.f, 0.f, 0.f, 0.f};

  mm_core<16, 1024, 1024>(eb + (size_t)(b * 1024 + R0) * 1024,
                          vt + (size_t)(b * 512 + C0) * 1024, As, Bs, acc);

  const float beta = beta_p[0];
  const int lane = threadIdx.x & 63, w = threadIdx.x >> 6;
  const int lr = lane & 15, lg = lane >> 4;
  const int wr = (w >> 1) * 64, wc = (w & 1) * 64;
  #pragma unroll
  for (int nf = 0; nf < 4; ++nf) {
    int col = C0 + wc + nf * 16 + lr;
    #pragma unroll
    for (int mf = 0; mf < 4; ++mf)
      #pragma unroll
      for (int i = 0; i < 4; i++) {
        int row = R0 + wr + mf * 16 + lg * 4 + i;
        float val = beta * acc[mf][nf][i] +
                    bf2f(vb[(size_t)(b * 1024 + row) * 512 + col]);
        outp[(size_t)(b * 1024 + row) * 512 + col] = val;
      }
  }
}

extern "C" void kernel_launch(void* const* d_in, const int* in_sizes, int n_in,
                              void* d_out, int out_size, void* d_ws, size_t ws_size,
                              hipStream_t stream) {
  (void)in_sizes; (void)n_in; (void)out_size; (void)ws_size;
  const float* x = (const float*)d_in[0];
  const float* Wq = (const float*)d_in[1];
  const float* bq = (const float*)d_in[2];
  const float* Wk = (const float*)d_in[3];
  const float* bk = (const float*)d_in[4];
  const float* Wv = (const float*)d_in[5];
  const float* bv = (const float*)d_in[6];
  const float* beta = (const float*)d_in[7];
  float* out = (float*)d_out;

  char* ws = (char*)d_ws;
  short* xb = (short*)(ws);                  // 32MB, reused as v_t after proj
  short* wb = (short*)(ws + 33554432);       // 1.5MB
  short* qb = (short*)(ws + 35127296);       // 32MB
  short* kb = (short*)(ws + 68681728);       // 32MB
  short* vb = (short*)(ws + 102236160);      // 32MB
  short* eb = (short*)(ws + 135790592);      // 64MB (E, then P in-place)
  short* vt = xb;

  cvt_kernel<<<8192, 256, 0, stream>>>(x, xb, 2097152);
  cvt_kernel<<<128, 256, 0, stream>>>(Wq, wb, 32768);
  cvt_kernel<<<128, 256, 0, stream>>>(Wk, wb + 262144, 32768);
  cvt_kernel<<<128, 256, 0, stream>>>(Wv, wb + 524288, 32768);
  proj_kernel<<<3072, 256, 0, stream>>>(xb, wb, bq, bk, bv, qb, kb, vb);
  transpose_kernel<<<dim3(8, 16, 32), 256, 0, stream>>>(vb, vt);
  qk_kernel<<<2048, 256, 0, stream>>>(qb, kb, eb);
  softmax_kernel<<<8192, 256, 0, stream>>>(eb);
  pv_kernel<<<1024, 256, 0, stream>>>(eb, vt, vb, beta, out);
}

// Round 6
// 225.807 us; speedup vs baseline: 2.1400x; 1.0485x over previous
//
#include <hip/hip_runtime.h>
#include <hip/hip_bf16.h>

typedef short s8v __attribute__((ext_vector_type(8)));   // 8 bf16 = 16B (4 VGPR)
typedef float f4v __attribute__((ext_vector_type(4)));   // MFMA accum

#define MFMA_BF16(a, b, c) __builtin_amdgcn_mfma_f32_16x16x32_bf16((a), (b), (c), 0, 0, 0)

// async global->LDS, 16B per lane; LDS dest = wave-uniform base + lane*16
#define GLDS16(g, l) __builtin_amdgcn_global_load_lds( \
    (const __attribute__((address_space(1))) void*)(g), \
    (__attribute__((address_space(3))) void*)(l), 16, 0, 0)

__device__ __forceinline__ short f2bf(float f) {
  __hip_bfloat16 h = __float2bfloat16(f);
  return *reinterpret_cast<short*>(&h);
}
__device__ __forceinline__ float bf2f(short s) {
  __hip_bfloat16 h;
  *reinterpret_cast<short*>(&h) = s;
  return __bfloat162float(h);
}

// ---------------- fp32 -> bf16 conversion ----------------
__global__ __launch_bounds__(256) void cvt_kernel(const float* __restrict__ in,
                                                  short* __restrict__ out, int n8) {
  int i = blockIdx.x * 256 + threadIdx.x;
  if (i >= n8) return;
  const float* p = in + (size_t)i * 8;
  float4 a = *(const float4*)p;
  float4 b = *(const float4*)(p + 4);
  s8v o;
  o[0] = f2bf(a.x); o[1] = f2bf(a.y); o[2] = f2bf(a.z); o[3] = f2bf(a.w);
  o[4] = f2bf(b.x); o[5] = f2bf(b.y); o[6] = f2bf(b.z); o[7] = f2bf(b.w);
  *(s8v*)(out + (size_t)i * 8) = o;
}

// ------- 2-phase double-buffered GEMM core: 128x128 tile, BK=64 -------
// A row-major [M][ASTR] over K; B row-major [N][BSTR] over K (B^T layout).
// Stage(t+1) issued BEFORE compute(t); single __syncthreads per K-step
// (drains vmcnt after compute -> load latency hidden under MFMA phase).
// XOR swizzle (row&7)<<4 on per-lane global source AND ds_read addr (rule 21).
template<int KSTEPS, int ASTR, int BSTR>
__device__ __forceinline__ void mm_core(const short* __restrict__ Abase,
                                        const short* __restrict__ Bbase,
                                        short* As0, short* Bs0,
                                        short* As1, short* Bs1,
                                        f4v (&acc)[4][4]) {
  const int t = threadIdx.x;
  const int lane = t & 63, w = t >> 6;
  const int lr = lane & 15, lg = lane >> 4;
  const int wr = (w >> 1) * 64, wc = (w & 1) * 64;
  const int srcc = ((lane & 7) * 16) ^ ((lane >> 3) << 4);  // swizzled src col byte
  const int rstage = w * 32 + (lane >> 3);

  auto stage = [&](short* As, short* Bs, int kt) {
    #pragma unroll
    for (int j = 0; j < 4; ++j)
      GLDS16((const char*)(Abase + (size_t)(rstage + j * 8) * ASTR) + kt * 128 + srcc,
             (char*)As + (w * 32 + j * 8) * 128);
    #pragma unroll
    for (int j = 0; j < 4; ++j)
      GLDS16((const char*)(Bbase + (size_t)(rstage + j * 8) * BSTR) + kt * 128 + srcc,
             (char*)Bs + (w * 32 + j * 8) * 128);
  };

  stage(As0, Bs0, 0);
  __syncthreads();
  short* Asc = As0; short* Bsc = Bs0;
  short* Asn = As1; short* Bsn = Bs1;
  for (int kt = 0; kt < KSTEPS; ++kt) {
    if (kt + 1 < KSTEPS) stage(Asn, Bsn, kt + 1);   // next tile in flight
    #pragma unroll
    for (int kk = 0; kk < 2; ++kk) {
      s8v af[4], bfr[4];
      #pragma unroll
      for (int mf = 0; mf < 4; ++mf)
        af[mf] = *(const s8v*)((const char*)Asc + (wr + mf * 16 + lr) * 128 +
                               ((kk * 64 + lg * 16) ^ ((lr & 7) << 4)));
      #pragma unroll
      for (int nf = 0; nf < 4; ++nf)
        bfr[nf] = *(const s8v*)((const char*)Bsc + (wc + nf * 16 + lr) * 128 +
                                ((kk * 64 + lg * 16) ^ ((lr & 7) << 4)));
      #pragma unroll
      for (int mf = 0; mf < 4; ++mf)
        #pragma unroll
        for (int nf = 0; nf < 4; ++nf)
          acc[mf][nf] = MFMA_BF16(af[mf], bfr[nf], acc[mf][nf]);
    }
    __syncthreads();   // drains vmcnt(0): next tile landed; this tile free
    short* ta = Asc; Asc = Asn; Asn = ta;
    short* tb = Bsc; Bsc = Bsn; Bsn = tb;
  }
}

// ---------------- projections: y = x @ W^T + b ----------------
__global__ __launch_bounds__(256) void proj_kernel(
    const short* __restrict__ xb, const short* __restrict__ wb,
    const float* __restrict__ bq, const float* __restrict__ bk, const float* __restrict__ bv,
    short* __restrict__ qo, short* __restrict__ ko, short* __restrict__ vo) {
  const int bx = blockIdx.x;
  const int L = (bx & 7) * 384 + (bx >> 3);   // bijective XCD swizzle (3072 = 8*384)
  const int cb = L & 3, rb = (L >> 2) & 255, mat = L >> 10;
  const int R0 = rb * 128, C0 = cb * 128;
  const float* bias = (mat == 0) ? bq : (mat == 1) ? bk : bv;
  short* out = (mat == 0) ? qo : (mat == 1) ? ko : vo;

  __shared__ short As0[8192], Bs0[8192], As1[8192], Bs1[8192];
  f4v acc[4][4];
  #pragma unroll
  for (int i = 0; i < 4; i++)
    #pragma unroll
    for (int j = 0; j < 4; j++) acc[i][j] = (f4v){0.f, 0.f, 0.f, 0.f};

  mm_core<8, 512, 512>(xb + (size_t)R0 * 512,
                       wb + (size_t)mat * 512 * 512 + (size_t)C0 * 512,
                       As0, Bs0, As1, Bs1, acc);

  const int lane = threadIdx.x & 63, w = threadIdx.x >> 6;
  const int lr = lane & 15, lg = lane >> 4;
  const int wr = (w >> 1) * 64, wc = (w & 1) * 64;
  #pragma unroll
  for (int nf = 0; nf < 4; ++nf) {
    int col = C0 + wc + nf * 16 + lr;
    float bb = bias[col];
    #pragma unroll
    for (int mf = 0; mf < 4; ++mf)
      #pragma unroll
      for (int i = 0; i < 4; i++) {
        int row = R0 + wr + mf * 16 + lg * 4 + i;
        out[(size_t)row * 512 + col] = f2bf(acc[mf][nf][i] + bb);
      }
  }
}

// ---------------- v (B,C,N) -> v_t (B,N,C) ----------------
__global__ __launch_bounds__(256) void transpose_kernel(const short* __restrict__ v,
                                                        short* __restrict__ vt) {
  const int nb = blockIdx.x;
  const int cbk = blockIdx.y;
  const int b = blockIdx.z;
  __shared__ short tile[64 * 72];
  const int t = threadIdx.x;
  const int r = t >> 2, qd = t & 3;
  const short* src = v + (size_t)(b * 1024 + cbk * 64 + r) * 512 + nb * 64 + qd * 16;
  s8v v0 = *(const s8v*)src;
  s8v v1 = *(const s8v*)(src + 8);
  *(s8v*)&tile[r * 72 + qd * 16] = v0;
  *(s8v*)&tile[r * 72 + qd * 16 + 8] = v1;
  __syncthreads();
  s8v o0, o1;
  #pragma unroll
  for (int j = 0; j < 8; j++) o0[j] = tile[(qd * 16 + j) * 72 + r];
  #pragma unroll
  for (int j = 0; j < 8; j++) o1[j] = tile[(qd * 16 + 8 + j) * 72 + r];
  short* dst = vt + (size_t)(b * 512 + nb * 64 + r) * 1024 + cbk * 64 + qd * 16;
  *(s8v*)dst = o0;
  *(s8v*)(dst + 8) = o1;
}

// ---------------- E = Q @ K^T per batch ----------------
__global__ __launch_bounds__(256) void qk_kernel(const short* __restrict__ qb,
                                                 const short* __restrict__ kb,
                                                 short* __restrict__ eb) {
  const int bx = blockIdx.x;
  const int L = (bx & 7) * 256 + (bx >> 3);   // 2048 = 8*256
  const int rb = L & 7, cb = (L >> 3) & 7, b = L >> 6;
  const int R0 = rb * 128, C0 = cb * 128;

  __shared__ short As0[8192], Bs0[8192], As1[8192], Bs1[8192];
  f4v acc[4][4];
  #pragma unroll
  for (int i = 0; i < 4; i++)
    #pragma unroll
    for (int j = 0; j < 4; j++) acc[i][j] = (f4v){0.f, 0.f, 0.f, 0.f};

  mm_core<8, 512, 512>(qb + (size_t)(b * 1024 + R0) * 512,
                       kb + (size_t)(b * 1024 + C0) * 512,
                       As0, Bs0, As1, Bs1, acc);

  const int lane = threadIdx.x & 63, w = threadIdx.x >> 6;
  const int lr = lane & 15, lg = lane >> 4;
  const int wr = (w >> 1) * 64, wc = (w & 1) * 64;
  #pragma unroll
  for (int nf = 0; nf < 4; ++nf) {
    int col = C0 + wc + nf * 16 + lr;
    #pragma unroll
    for (int mf = 0; mf < 4; ++mf)
      #pragma unroll
      for (int i = 0; i < 4; i++) {
        int row = R0 + wr + mf * 16 + lg * 4 + i;
        eb[(size_t)(b * 1024 + row) * 1024 + col] = f2bf(acc[mf][nf][i]);
      }
  }
}

// ---------------- in-place row softmax (rows of 1024 bf16) ----------------
__global__ __launch_bounds__(256) void softmax_kernel(short* __restrict__ eb) {
  const int row = blockIdx.x * 4 + (threadIdx.x >> 6);
  const int lane = threadIdx.x & 63;
  short* p = eb + (size_t)row * 1024 + lane * 16;
  s8v a = *(const s8v*)p;
  s8v bvv = *(const s8v*)(p + 8);
  float v[16];
  #pragma unroll
  for (int j = 0; j < 8; j++) { v[j] = bf2f(a[j]); v[8 + j] = bf2f(bvv[j]); }
  float m = v[0];
  #pragma unroll
  for (int j = 1; j < 16; j++) m = fmaxf(m, v[j]);
  #pragma unroll
  for (int s = 1; s <= 32; s <<= 1) m = fmaxf(m, __shfl_xor(m, s));
  float l = 0.f;
  #pragma unroll
  for (int j = 0; j < 16; j++) { v[j] = __expf(v[j] - m); l += v[j]; }
  #pragma unroll
  for (int s = 1; s <= 32; s <<= 1) l += __shfl_xor(l, s);
  const float inv = 1.0f / l;
  s8v o0, o1;
  #pragma unroll
  for (int j = 0; j < 8; j++) { o0[j] = f2bf(v[j] * inv); o1[j] = f2bf(v[8 + j] * inv); }
  *(s8v*)p = o0;
  *(s8v*)(p + 8) = o1;
}

// ---------------- out = beta * (P @ V) + v ----------------
__global__ __launch_bounds__(256) void pv_kernel(const short* __restrict__ eb,
                                                 const short* __restrict__ vt,
                                                 const short* __restrict__ vb,
                                                 const float* __restrict__ beta_p,
                                                 float* __restrict__ outp) {
  const int bx = blockIdx.x;
  const int L = (bx & 7) * 128 + (bx >> 3);   // 1024 = 8*128
  const int cb = L & 3, rb = (L >> 2) & 7, b = L >> 5;
  const int R0 = rb * 128, C0 = cb * 128;

  __shared__ short As0[8192], Bs0[8192], As1[8192], Bs1[8192];
  f4v acc[4][4];
  #pragma unroll
  for (int i = 0; i < 4; i++)
    #pragma unroll
    for (int j = 0; j < 4; j++) acc[i][j] = (f4v){0.f, 0.f, 0.f, 0.f};

  mm_core<16, 1024, 1024>(eb + (size_t)(b * 1024 + R0) * 1024,
                          vt + (size_t)(b * 512 + C0) * 1024,
                          As0, Bs0, As1, Bs1, acc);

  const float beta = beta_p[0];
  const int lane = threadIdx.x & 63, w = threadIdx.x >> 6;
  const int lr = lane & 15, lg = lane >> 4;
  const int wr = (w >> 1) * 64, wc = (w & 1) * 64;
  #pragma unroll
  for (int nf = 0; nf < 4; ++nf) {
    int col = C0 + wc + nf * 16 + lr;
    #pragma unroll
    for (int mf = 0; mf < 4; ++mf)
      #pragma unroll
      for (int i = 0; i < 4; i++) {
        int row = R0 + wr + mf * 16 + lg * 4 + i;
        float val = beta * acc[mf][nf][i] +
                    bf2f(vb[(size_t)(b * 1024 + row) * 512 + col]);
        outp[(size_t)(b * 1024 + row) * 512 + col] = val;
      }
  }
}

extern "C" void kernel_launch(void* const* d_in, const int* in_sizes, int n_in,
                              void* d_out, int out_size, void* d_ws, size_t ws_size,
                              hipStream_t stream) {
  (void)in_sizes; (void)n_in; (void)out_size; (void)ws_size;
  const float* x = (const float*)d_in[0];
  const float* Wq = (const float*)d_in[1];
  const float* bq = (const float*)d_in[2];
  const float* Wk = (const float*)d_in[3];
  const float* bk = (const float*)d_in[4];
  const float* Wv = (const float*)d_in[5];
  const float* bv = (const float*)d_in[6];
  const float* beta = (const float*)d_in[7];
  float* out = (float*)d_out;

  char* ws = (char*)d_ws;
  short* xb = (short*)(ws);                  // 32MB, reused as v_t after proj
  short* wb = (short*)(ws + 33554432);       // 1.5MB
  short* qb = (short*)(ws + 35127296);       // 32MB
  short* kb = (short*)(ws + 68681728);       // 32MB
  short* vb = (short*)(ws + 102236160);      // 32MB
  short* eb = (short*)(ws + 135790592);      // 64MB (E, then P in-place)
  short* vt = xb;

  cvt_kernel<<<8192, 256, 0, stream>>>(x, xb, 2097152);
  cvt_kernel<<<128, 256, 0, stream>>>(Wq, wb, 32768);
  cvt_kernel<<<128, 256, 0, stream>>>(Wk, wb + 262144, 32768);
  cvt_kernel<<<128, 256, 0, stream>>>(Wv, wb + 524288, 32768);
  proj_kernel<<<3072, 256, 0, stream>>>(xb, wb, bq, bk, bv, qb, kb, vb);
  transpose_kernel<<<dim3(8, 16, 32), 256, 0, stream>>>(vb, vt);
  qk_kernel<<<2048, 256, 0, stream>>>(qb, kb, eb);
  softmax_kernel<<<8192, 256, 0, stream>>>(eb);
  pv_kernel<<<1024, 256, 0, stream>>>(eb, vt, vb, beta, out);
}